// Round 8
// baseline (290.530 us; speedup 1.0000x reference)
//
#include <hip/hip_runtime.h>
#include <hip/hip_bf16.h>
#include <math.h>

static constexpr int DM = 1024;   // d_model
static constexpr int NH = 16;     // heads
static constexpr int DH = 64;     // head dim
static constexpr int QKV = 3 * DM;

typedef __attribute__((ext_vector_type(8))) short short8v;  // 8 bf16 = 4 VGPR
typedef __attribute__((ext_vector_type(4))) float f32x4;

__device__ inline short f2bf(float x) {
    __hip_bfloat16 h = __float2bfloat16(x);
    return *reinterpret_cast<short*>(&h);
}

// async global->LDS, 16B per lane. LDS dst must be wave-uniform (HW writes
// lane i at dst + i*16); global src is per-lane.
__device__ inline void gload16(const void* g, void* l) {
    __builtin_amdgcn_global_load_lds(
        (const __attribute__((address_space(1))) unsigned int*)g,
        (__attribute__((address_space(3))) unsigned int*)l, 16, 0, 0);
}

// ---------------------------------------------------------------------------
// Fused fp32 -> bf16 convert for all five inputs (one launch).
// ---------------------------------------------------------------------------
__global__ __launch_bounds__(256)
void convert_inputs(const float* __restrict__ x,  const float* __restrict__ wq,
                    const float* __restrict__ wk, const float* __restrict__ wv,
                    const float* __restrict__ wo, short* __restrict__ xh,
                    short* __restrict__ wqkv, short* __restrict__ woh,
                    int nx, int nw) {
    const int i = (blockIdx.x * 256 + threadIdx.x) * 4;
    const float* src;
    short* dst;
    int off;
    if (i < nx)                { src = x;  dst = xh;            off = i; }
    else if (i < nx + nw)      { src = wq; dst = wqkv;          off = i - nx; }
    else if (i < nx + 2 * nw)  { src = wk; dst = wqkv + nw;     off = i - nx - nw; }
    else if (i < nx + 3 * nw)  { src = wv; dst = wqkv + 2 * nw; off = i - nx - 2 * nw; }
    else if (i < nx + 4 * nw)  { src = wo; dst = woh;           off = i - nx - 3 * nw; }
    else return;
    const float4 v = *(const float4*)(src + off);
    short4 o;
    o.x = f2bf(v.x); o.y = f2bf(v.y); o.z = f2bf(v.z); o.w = f2bf(v.w);
    *(short4*)(dst + off) = o;
}

// ---------------------------------------------------------------------------
// bf16 MFMA GEMM, m97 structure (unchanged, passing).
// ---------------------------------------------------------------------------
template <int BF16OUT>
__global__ __launch_bounds__(256)
void gemm_bt_mfma(const short* __restrict__ A, const short* __restrict__ B,
                  void* __restrict__ Cv, int M, int N, int K) {
    __shared__ __align__(16) short As[128 * 32];
    __shared__ __align__(16) short Bs[128 * 32];
    const int tid = threadIdx.x;
    const int w = tid >> 6, l = tid & 63;
    const int lo = l & 15, hi = l >> 4;
    const int wr = w >> 1, wc = w & 1;
    const size_t m0 = (size_t)blockIdx.y * 128;
    const size_t n0 = (size_t)blockIdx.x * 128;

    const int cr = (w * 2) * 16 + (l >> 2);
    const int cc = (l & 3) * 8;
    const short* Ag0 = A + (m0 + cr) * K + cc;
    const short* Ag1 = Ag0 + (size_t)16 * K;
    const short* Bg0 = B + (n0 + cr) * K + cc;
    const short* Bg1 = Bg0 + (size_t)16 * K;
    short* As0 = As + (w * 2) * 512;
    short* As1 = As0 + 512;
    short* Bs0 = Bs + (w * 2) * 512;
    short* Bs1 = Bs0 + 512;

    f32x4 acc[4][4];
    #pragma unroll
    for (int mi = 0; mi < 4; ++mi)
        #pragma unroll
        for (int nj = 0; nj < 4; ++nj)
            acc[mi][nj] = (f32x4){0.f, 0.f, 0.f, 0.f};

    const int aoff = (wr * 64 + lo) * 32 + hi * 8;
    const int boff = (wc * 64 + lo) * 32 + hi * 8;

    for (int k0 = 0; k0 < K; k0 += 32) {
        __syncthreads();
        gload16(Ag0 + k0, As0);
        gload16(Ag1 + k0, As1);
        gload16(Bg0 + k0, Bs0);
        gload16(Bg1 + k0, Bs1);
        __syncthreads();
        short8v af[4], bf[4];
        #pragma unroll
        for (int mi = 0; mi < 4; ++mi)
            af[mi] = *(const short8v*)&As[aoff + mi * 16 * 32];
        #pragma unroll
        for (int nj = 0; nj < 4; ++nj)
            bf[nj] = *(const short8v*)&Bs[boff + nj * 16 * 32];
        #pragma unroll
        for (int mi = 0; mi < 4; ++mi)
            #pragma unroll
            for (int nj = 0; nj < 4; ++nj)
                acc[mi][nj] = __builtin_amdgcn_mfma_f32_16x16x32_bf16(
                    af[mi], bf[nj], acc[mi][nj], 0, 0, 0);
    }

    const size_t mbase = m0 + wr * 64 + hi * 4;
    const size_t nbase = n0 + wc * 64 + lo;
    #pragma unroll
    for (int mi = 0; mi < 4; ++mi)
        #pragma unroll
        for (int nj = 0; nj < 4; ++nj)
            #pragma unroll
            for (int rg = 0; rg < 4; ++rg) {
                const size_t m = mbase + mi * 16 + rg;
                const size_t n = nbase + nj * 16;
                if (BF16OUT)
                    ((short*)Cv)[m * N + n] = f2bf(acc[mi][nj][rg]);
                else
                    ((float*)Cv)[m * N + n] = acc[mi][nj][rg];
            }
}

// ---------------------------------------------------------------------------
// RoPE on bf16 QKV buffer (Q scaled by 1/8). (unchanged, passing)
// ---------------------------------------------------------------------------
__global__ __launch_bounds__(256)
void rope_bf16(const short* __restrict__ QKVr, const int* __restrict__ pos,
               short* __restrict__ Qh, short* __restrict__ Kh, int S, int rows) {
    int idx = blockIdx.x * 256 + threadIdx.x;
    const int per = rows * (DM / 2);
    bool isK = false;
    if (idx >= per) { idx -= per; isK = true; }
    if (idx >= per) return;
    const int row = idx >> 9;
    const int rem = idx & 511;
    const int h = rem >> 5, k = rem & 31;
    const unsigned pin = *(const unsigned*)(QKVr + (size_t)row * QKV +
                                            (isK ? DM : 0) + h * DH + 2 * k);
    const float x0 = __uint_as_float(pin << 16);
    const float x1 = __uint_as_float(pin & 0xffff0000u);
    const float ang = (float)pos[row % S] * powf(10000.0f, -(float)k * (1.0f / 32.0f));
    const float c = cosf(ang), sn = sinf(ang);
    float y0 = c * x0 - sn * x1;
    float y1 = sn * x0 + c * x1;
    if (!isK) { y0 *= 0.125f; y1 *= 0.125f; }
    const int b = row / S, sr = row % S;
    short* dst = (isK ? Kh : Qh) + ((size_t)(b * NH + h) * S + sr) * DH + 2 * k;
    *(unsigned*)dst = ((unsigned)(unsigned short)f2bf(y1) << 16)
                    | (unsigned short)f2bf(y0);
}

// ---------------------------------------------------------------------------
// V slice of QKV buffer -> per-head transposed Vt[B*H][64][S]. (unchanged)
// ---------------------------------------------------------------------------
__global__ __launch_bounds__(256)
void v_transpose_bf16(const short* __restrict__ QKVr, short* __restrict__ Vt, int S) {
    __shared__ __align__(16) short T[64][72];
    const int bh = blockIdx.y;
    const int b = bh / NH, h = bh - b * NH;
    const int s0 = blockIdx.x * 64;
    const int tid = threadIdx.x;
    const int r = tid >> 2, seg = (tid & 3) * 16;
    const short* src = QKVr + (size_t)(b * S + s0 + r) * QKV + 2 * DM + h * DH + seg;
    const short8v a0 = *(const short8v*)(src);
    const short8v a1 = *(const short8v*)(src + 8);
    #pragma unroll
    for (int j = 0; j < 8; ++j) T[seg + j][r] = a0[j];
    #pragma unroll
    for (int j = 0; j < 8; ++j) T[seg + 8 + j][r] = a1[j];
    __syncthreads();
    const uint4* sv = (const uint4*)&T[r][seg];
    uint4* dv = (uint4*)&Vt[((size_t)bh * DH + r) * S + s0 + seg];
    dv[0] = sv[0]; dv[1] = sv[1];
}

// ---------------------------------------------------------------------------
// MFMA flash attention, R8 = R7 + KV-SPLIT (2 waves per q-tile pair).
// Block = 512 thr = 8 waves = 4 pairs x 2 halves. Half h processes kv
// blocks kb = h, h+2, ... (interleaved -> balanced for both tiles) with the
// unchanged R7 online-softmax loop. Then: barrier; odd half writes
// (o, m, la) to LDS (aliased over the dead P buffer); barrier; even half
// merges (flash combine, exact fp32) and writes output.
// Doubles TLP: 4096 waves = 16/CU = 4/SIMD (launch_bounds caps VGPR<=128).
// ---------------------------------------------------------------------------
__global__ __launch_bounds__(512, 4)
void attn_mfma(const short* __restrict__ Qh, const short* __restrict__ Kh,
               const short* __restrict__ Vt, short* __restrict__ Oh, int S) {
    // P region: [8 waves][2 tiles][16][72] bf16 = 36864 B (loop phase).
    // Merge region: [4 pairs][2 tiles][64 lanes][24] f32 = 49152 B (after
    // barrier; aliases P — safe, separated by __syncthreads).
    __shared__ __align__(16) char smem[49152];
    auto P = (__hip_bfloat16 (*)[2][16][72])smem;
    float* MB = (float*)smem;

    const int b = blockIdx.z, h = blockIdx.y;
    const int bh = b * NH + h;
    const int tid = threadIdx.x;
    const int w = tid >> 6, l = tid & 63;
    const int pw = w >> 1, half = w & 1;
    const int lo = l & 15, hi = l >> 4;
    const int T = S >> 4;
    const int p = blockIdx.x * 4 + pw;
    const int q0B = (T - 1 - p) << 4;
    const int q0F = p << 4;
    const int nkbB = (q0B + 79) >> 6;
    const int nkbF = (q0F + 79) >> 6;

    const short* Qp = Qh + (size_t)bh * S * DH;
    const short* Kp = Kh + (size_t)bh * S * DH;
    const short* Vp = Vt + (size_t)bh * DH * S;

    const short8v qB0 = *(const short8v*)(Qp + (size_t)(q0B + lo) * DH + hi * 8);
    const short8v qB1 = *(const short8v*)(Qp + (size_t)(q0B + lo) * DH + 32 + hi * 8);
    const short8v qF0 = *(const short8v*)(Qp + (size_t)(q0F + lo) * DH + hi * 8);
    const short8v qF1 = *(const short8v*)(Qp + (size_t)(q0F + lo) * DH + 32 + hi * 8);

    short8v ones;
    #pragma unroll
    for (int i = 0; i < 8; ++i) ones[i] = (short)0x3F80;   // bf16 1.0

    f32x4 oB[4], oF[4];
    f32x4 laB = (f32x4){0.f, 0.f, 0.f, 0.f};
    f32x4 laF = (f32x4){0.f, 0.f, 0.f, 0.f};
    float mB[4], mF[4];
    #pragma unroll
    for (int i = 0; i < 4; ++i) {
        oB[i] = (f32x4){0.f, 0.f, 0.f, 0.f};
        oF[i] = (f32x4){0.f, 0.f, 0.f, 0.f};
        mB[i] = -INFINITY; mF[i] = -INFINITY;
    }
    const f32x4 z = (f32x4){0.f, 0.f, 0.f, 0.f};
    const float THR = 8.0f;

    auto softmaxTile = [&](f32x4 (&s)[4], f32x4 (&o)[4], f32x4& la,
                           float (&m)[4], bool masked, int q0, int kvb, int tsel) {
        float sv[4][4], pmax[4];
        #pragma unroll
        for (int rg = 0; rg < 4; ++rg) {
            #pragma unroll
            for (int kt = 0; kt < 4; ++kt) {
                float v = s[kt][rg];
                if (masked && (kvb + kt * 16 + lo > q0 + hi * 4 + rg)) v = -INFINITY;
                sv[rg][kt] = v;
            }
            pmax[rg] = fmaxf(fmaxf(sv[rg][0], sv[rg][1]),
                             fmaxf(sv[rg][2], sv[rg][3]));
        }
        int need = 0;
        #pragma unroll
        for (int rg = 0; rg < 4; ++rg) need |= (pmax[rg] > m[rg] + THR);
        if (__any(need)) {
            #pragma unroll
            for (int rg = 0; rg < 4; ++rg) {
                float bm = pmax[rg];
                bm = fmaxf(bm, __shfl_xor(bm, 1));
                bm = fmaxf(bm, __shfl_xor(bm, 2));
                bm = fmaxf(bm, __shfl_xor(bm, 4));
                bm = fmaxf(bm, __shfl_xor(bm, 8));
                const float mn = fmaxf(m[rg], bm);
                const float c = __expf(m[rg] - mn);
                m[rg] = mn;
                la[rg] *= c;
                #pragma unroll
                for (int dt = 0; dt < 4; ++dt) o[dt][rg] *= c;
            }
        }
        #pragma unroll
        for (int rg = 0; rg < 4; ++rg)
            #pragma unroll
            for (int kt = 0; kt < 4; ++kt)
                P[w][tsel][hi * 4 + rg][kt * 16 + lo] =
                    __float2bfloat16(__expf(sv[rg][kt] - m[rg]));
    };

    for (int kb = half; kb < nkbB; kb += 2) {
        const int kvb = kb * 64;
        const bool actF = kb < nkbF;

        short8v kf0[4], kf1[4];
        #pragma unroll
        for (int kt = 0; kt < 4; ++kt) {
            const short* kbase = Kp + (size_t)(kvb + kt * 16 + lo) * DH + hi * 8;
            kf0[kt] = *(const short8v*)(kbase);
            kf1[kt] = *(const short8v*)(kbase + 32);
        }
        short8v vf0[4], vf1[4];
        #pragma unroll
        for (int dt = 0; dt < 4; ++dt) {
            const short* vbase = Vp + (size_t)(dt * 16 + lo) * S + kvb + hi * 8;
            vf0[dt] = *(const short8v*)(vbase);
            vf1[dt] = *(const short8v*)(vbase + 32);
        }

        f32x4 sB[4], sF[4];
        #pragma unroll
        for (int kt = 0; kt < 4; ++kt) {
            f32x4 a = z;
            a = __builtin_amdgcn_mfma_f32_16x16x32_bf16(qB0, kf0[kt], a, 0, 0, 0);
            a = __builtin_amdgcn_mfma_f32_16x16x32_bf16(qB1, kf1[kt], a, 0, 0, 0);
            sB[kt] = a;
        }
        if (actF) {
            #pragma unroll
            for (int kt = 0; kt < 4; ++kt) {
                f32x4 a = z;
                a = __builtin_amdgcn_mfma_f32_16x16x32_bf16(qF0, kf0[kt], a, 0, 0, 0);
                a = __builtin_amdgcn_mfma_f32_16x16x32_bf16(qF1, kf1[kt], a, 0, 0, 0);
                sF[kt] = a;
            }
        }

        softmaxTile(sB, oB, laB, mB, kb == nkbB - 1, q0B, kvb, 0);
        if (actF) softmaxTile(sF, oF, laF, mF, kb == nkbF - 1, q0F, kvb, 1);

        asm volatile("s_waitcnt lgkmcnt(0)" ::: "memory");
        const short8v paB0 = *(const short8v*)&P[w][0][lo][hi * 8];
        const short8v paB1 = *(const short8v*)&P[w][0][lo][32 + hi * 8];
        const short8v paF0 = *(const short8v*)&P[w][1][lo][hi * 8];
        const short8v paF1 = *(const short8v*)&P[w][1][lo][32 + hi * 8];

        laB = __builtin_amdgcn_mfma_f32_16x16x32_bf16(paB0, ones, laB, 0, 0, 0);
        laB = __builtin_amdgcn_mfma_f32_16x16x32_bf16(paB1, ones, laB, 0, 0, 0);
        if (actF) {
            laF = __builtin_amdgcn_mfma_f32_16x16x32_bf16(paF0, ones, laF, 0, 0, 0);
            laF = __builtin_amdgcn_mfma_f32_16x16x32_bf16(paF1, ones, laF, 0, 0, 0);
        }

        #pragma unroll
        for (int dt = 0; dt < 4; ++dt) {
            oB[dt] = __builtin_amdgcn_mfma_f32_16x16x32_bf16(paB0, vf0[dt], oB[dt], 0, 0, 0);
            oB[dt] = __builtin_amdgcn_mfma_f32_16x16x32_bf16(paB1, vf1[dt], oB[dt], 0, 0, 0);
            if (actF) {
                oF[dt] = __builtin_amdgcn_mfma_f32_16x16x32_bf16(paF0, vf0[dt], oF[dt], 0, 0, 0);
                oF[dt] = __builtin_amdgcn_mfma_f32_16x16x32_bf16(paF1, vf1[dt], oF[dt], 0, 0, 0);
            }
        }
    }

    // ---- KV-split combine ----
    __syncthreads();                 // all loops done; P region now dead
    if (half == 1) {
        #pragma unroll
        for (int t = 0; t < 2; ++t) {
            float* dst = MB + (size_t)(((pw * 2 + t) * 64) + l) * 24;
            f32x4* o = (t == 0) ? oB : oF;
            #pragma unroll
            for (int dt = 0; dt < 4; ++dt) ((f32x4*)dst)[dt] = o[dt];
            float* m = (t == 0) ? mB : mF;
            ((f32x4*)dst)[4] = (f32x4){m[0], m[1], m[2], m[3]};
            ((f32x4*)dst)[5] = (t == 0) ? laB : laF;
        }
    }
    __syncthreads();
    if (half == 0) {
        #pragma unroll
        for (int t = 0; t < 2; ++t) {
            const float* src = MB + (size_t)(((pw * 2 + t) * 64) + l) * 24;
            f32x4* o = (t == 0) ? oB : oF;
            float* m = (t == 0) ? mB : mF;
            f32x4& la = (t == 0) ? laB : laF;
            const f32x4 m1 = ((const f32x4*)src)[4];
            const f32x4 la1 = ((const f32x4*)src)[5];
            float iv[4];
            #pragma unroll
            for (int rg = 0; rg < 4; ++rg) {
                const float mst = fmaxf(m[rg], m1[rg]);
                const float c0 = __expf(m[rg] - mst);
                const float c1 = __expf(m1[rg] - mst);
                const float lm = la[rg] * c0 + la1[rg] * c1;
                iv[rg] = 1.0f / lm;
                #pragma unroll
                for (int dt = 0; dt < 4; ++dt) {
                    const f32x4 o1 = ((const f32x4*)src)[dt];
                    o[dt][rg] = o[dt][rg] * c0 + o1[rg] * c1;
                }
            }
            const int q0 = (t == 0) ? q0B : q0F;
            short* Op = Oh + (size_t)(b * S + q0) * DM + h * DH;
            #pragma unroll
            for (int rg = 0; rg < 4; ++rg)
                #pragma unroll
                for (int dt = 0; dt < 4; ++dt)
                    Op[(size_t)(hi * 4 + rg) * DM + dt * 16 + lo] =
                        f2bf(o[dt][rg] * iv[rg]);
        }
    }
}

// ---------------------------------------------------------------------------
extern "C" void kernel_launch(void* const* d_in, const int* in_sizes, int n_in,
                              void* d_out, int out_size, void* d_ws, size_t ws_size,
                              hipStream_t stream) {
    const float* x  = (const float*)d_in[0];
    const int*  pos = (const int*)d_in[1];
    const float* wq = (const float*)d_in[2];
    const float* wk = (const float*)d_in[3];
    const float* wv = (const float*)d_in[4];
    const float* wo = (const float*)d_in[5];
    float* out = (float*)d_out;

    const int S = in_sizes[1];              // 2048
    const int rows = in_sizes[0] / DM;      // B*S
    const int Bb = rows / S;

    short* xh   = (short*)d_ws;
    short* wqkv = xh + (size_t)rows * DM;
    short* woh  = wqkv + (size_t)QKV * DM;
    short* QKVr = woh + (size_t)DM * DM;
    short* Qh   = QKVr + (size_t)rows * QKV;
    short* Kh   = Qh + (size_t)rows * DM;
    short* Vt   = Kh + (size_t)rows * DM;
    short* Oh   = Vt + (size_t)rows * DM;

    const int nx = rows * DM;
    const int nw = DM * DM;
    const int ntot = nx + 4 * nw;
    convert_inputs<<<(ntot / 4 + 255) / 256, 256, 0, stream>>>(
        x, wq, wk, wv, wo, xh, wqkv, woh, nx, nw);

    gemm_bt_mfma<1><<<dim3(QKV / 128, rows / 128), 256, 0, stream>>>(
        xh, wqkv, QKVr, rows, QKV, DM);

    const int total = 2 * rows * (DM / 2);
    rope_bf16<<<(total + 255) / 256, 256, 0, stream>>>(QKVr, pos, Qh, Kh, S, rows);
    v_transpose_bf16<<<dim3(S / 64, Bb * NH), 256, 0, stream>>>(QKVr, Vt, S);

    attn_mfma<<<dim3(S / 128, NH, Bb), 512, 0, stream>>>(Qh, Kh, Vt, Oh, S);

    gemm_bt_mfma<0><<<dim3(DM / 128, rows / 128), 256, 0, stream>>>(
        Oh, woh, out, rows, DM, DM);
}